// Round 6
// baseline (410.205 us; speedup 1.0000x reference)
//
#include <hip/hip_runtime.h>
#include <cstdint>

constexpr int kDM = 2048;   // d_model
constexpr int kNH = 16;     // heads
constexpr int kDH = 128;    // head dim
constexpr int kS  = 2048;   // seq
constexpr int kM  = 4096;   // B*S rows

typedef __bf16 bf16x8 __attribute__((ext_vector_type(8)));
typedef float  f32x4  __attribute__((ext_vector_type(4)));

__device__ __forceinline__ unsigned short f2bf(float f) {
    union { float f; unsigned u; } v; v.f = f;
    unsigned u = v.u;
    u += 0x7fffu + ((u >> 16) & 1u);   // RNE
    return (unsigned short)(u >> 16);
}
__device__ __forceinline__ float fast_exp2(float x) {
#if __has_builtin(__builtin_amdgcn_exp2f)
    return __builtin_amdgcn_exp2f(x);
#else
    return exp2f(x);
#endif
}
// async global->LDS, 16B per lane, LDS dest = wave-uniform base + lane*16
__device__ __forceinline__ void load_lds16(const void* g, void* l) {
    auto gp = (__attribute__((address_space(1))) unsigned int*)(uintptr_t)g;
    auto lp = (__attribute__((address_space(3))) unsigned int*)(uintptr_t)l;
    __builtin_amdgcn_global_load_lds(gp, lp, 16, 0, 0);
}

// ---------------- LayerNorm: fp32 in -> bf16 out ----------------
__global__ __launch_bounds__(256) void ln_kernel(const float* __restrict__ X,
        const float* __restrict__ g, const float* __restrict__ b,
        unsigned short* __restrict__ Xn) {
    const int row = blockIdx.x;
    const float* xr = X + (size_t)row * kDM;
    const float4 v0 = ((const float4*)xr)[threadIdx.x];
    const float4 v1 = ((const float4*)xr)[threadIdx.x + 256];
    float s  = v0.x + v0.y + v0.z + v0.w + v1.x + v1.y + v1.z + v1.w;
    float sq = v0.x*v0.x + v0.y*v0.y + v0.z*v0.z + v0.w*v0.w
             + v1.x*v1.x + v1.y*v1.y + v1.z*v1.z + v1.w*v1.w;
    #pragma unroll
    for (int m = 1; m < 64; m <<= 1) { s += __shfl_xor(s, m); sq += __shfl_xor(sq, m); }
    __shared__ float ls[4], lq[4];
    if ((threadIdx.x & 63) == 0) { ls[threadIdx.x >> 6] = s; lq[threadIdx.x >> 6] = sq; }
    __syncthreads();
    s  = ls[0] + ls[1] + ls[2] + ls[3];
    sq = lq[0] + lq[1] + lq[2] + lq[3];
    const float mu   = s * (1.0f / kDM);
    const float rstd = rsqrtf(sq * (1.0f / kDM) - mu * mu + 1e-5f);
    unsigned short* xo = Xn + (size_t)row * kDM;
    {
        const float4 gg = ((const float4*)g)[threadIdx.x];
        const float4 bb = ((const float4*)b)[threadIdx.x];
        ushort4 o;
        o.x = f2bf((v0.x - mu) * rstd * gg.x + bb.x);
        o.y = f2bf((v0.y - mu) * rstd * gg.y + bb.y);
        o.z = f2bf((v0.z - mu) * rstd * gg.z + bb.z);
        o.w = f2bf((v0.w - mu) * rstd * gg.w + bb.w);
        ((ushort4*)xo)[threadIdx.x] = o;
    }
    {
        const float4 gg = ((const float4*)g)[threadIdx.x + 256];
        const float4 bb = ((const float4*)b)[threadIdx.x + 256];
        ushort4 o;
        o.x = f2bf((v1.x - mu) * rstd * gg.x + bb.x);
        o.y = f2bf((v1.y - mu) * rstd * gg.y + bb.y);
        o.z = f2bf((v1.z - mu) * rstd * gg.z + bb.z);
        o.w = f2bf((v1.w - mu) * rstd * gg.w + bb.w);
        ((ushort4*)xo)[threadIdx.x + 256] = o;
    }
}

// ------------- weight transpose+cast: W[K][N] f32 -> Wt[N][K] bf16 -------------
__global__ __launch_bounds__(256) void wt_kernel(
        const float* __restrict__ W0, const float* __restrict__ W1,
        const float* __restrict__ W2, const float* __restrict__ W3,
        unsigned short* __restrict__ T0, unsigned short* __restrict__ T1,
        unsigned short* __restrict__ T2, unsigned short* __restrict__ T3) {
    const float* W; unsigned short* T;
    switch (blockIdx.z) {
        case 0:  W = W0; T = T0; break;
        case 1:  W = W1; T = T1; break;
        case 2:  W = W2; T = T2; break;
        default: W = W3; T = T3; break;
    }
    __shared__ float tile[32][33];
    const int tx = threadIdx.x & 31, ty = threadIdx.x >> 5;
    const int r0 = blockIdx.y * 32, c0 = blockIdx.x * 32;
    #pragma unroll
    for (int i = 0; i < 4; ++i)
        tile[ty + i * 8][tx] = W[(size_t)(r0 + ty + i * 8) * kDM + c0 + tx];
    __syncthreads();
    #pragma unroll
    for (int i = 0; i < 4; ++i)
        T[(size_t)(c0 + ty + i * 8) * kDM + r0 + tx] = f2bf(tile[tx][ty + i * 8]);
}

// --- bias concat: [bq|bk|bv] -> 6144 floats ---
__global__ __launch_bounds__(256) void bias_pack(const float* __restrict__ bq,
        const float* __restrict__ bk, const float* __restrict__ bv,
        float* __restrict__ o) {
    const int i = blockIdx.x * 256 + threadIdx.x;
    o[i] = (i < 2048) ? bq[i] : ((i < 4096) ? bk[i - 2048] : bv[i - 4096]);
}

// --- V transpose: [bh][s][dh] bf16 -> [bh][dh][s] bf16, 64x64 tiles ---
__global__ __launch_bounds__(256) void vtr_kernel(const unsigned short* __restrict__ Vin,
                                                  unsigned short* __restrict__ Vout) {
    __shared__ __align__(16) unsigned short tile[64 * 72];
    const int bhz = blockIdx.z;
    const int s0 = blockIdx.x * 64, d0 = blockIdx.y * 64;
    const int t = threadIdx.x;
    const unsigned short* src = Vin + ((size_t)bhz * kS + s0) * kDH + d0;
    #pragma unroll
    for (int i = 0; i < 2; ++i) {
        const int r = (t >> 3) + 32 * i;
        const int g = t & 7;
        *(uint4*)(tile + r * 72 + g * 8) = *(const uint4*)(src + (size_t)r * kDH + g * 8);
    }
    __syncthreads();
    unsigned short* dst = Vout + ((size_t)bhz * kDH + d0) * kS + s0;
    #pragma unroll
    for (int i = 0; i < 2; ++i) {
        const int d = (t >> 3) + 32 * i;
        const int sg = t & 7;
        union { unsigned short u[8]; uint4 v; } o;
        #pragma unroll
        for (int j = 0; j < 8; ++j)
            o.u[j] = tile[(sg * 8 + j) * 72 + d];
        *(uint4*)(dst + (size_t)d * kS + sg * 8) = o.v;
    }
}

// ------------- GEMM: C = A[M,K]bf16 @ Bt[N,K]^T bf16 + bias -------------
// BK=64 via two 32-k sub-buffers; ascending-contiguous staging (R4: source
// swizzle breaks VMEM coalescing).  blockIdx.x = m-tile (fastest).
__global__ __launch_bounds__(256) void gemm_kernel(
        const unsigned short* __restrict__ A, const unsigned short* __restrict__ Bt,
        const float* __restrict__ bias, void* __restrict__ C0, void* __restrict__ C1,
        void* __restrict__ C2, const float scale0, const int fp32out) {
    __shared__ __align__(16) unsigned short ldsA[2][128 * 32];
    __shared__ __align__(16) unsigned short ldsB[2][128 * 32];
    const int m0 = blockIdx.x * 128, n0 = blockIdx.y * 128;
    const int tid = threadIdx.x, lane = tid & 63, w = tid >> 6;
    const int wm = (w >> 1) * 64, wn = (w & 1) * 64;
    const int quad = lane >> 4, l15 = lane & 15;
    f32x4 acc[4][4] = {};
    const int srow = lane >> 2, scol = (lane & 3) * 8;
    for (int k0 = 0; k0 < kDM; k0 += 64) {
        __syncthreads();
        #pragma unroll
        for (int sub = 0; sub < 2; ++sub) {
            #pragma unroll
            for (int i = 0; i < 2; ++i) {
                const int c = w + i * 4;
                const int row = c * 16 + srow;
                const int kc = k0 + sub * 32 + scol;
                load_lds16(A  + (size_t)(m0 + row) * kDM + kc, &ldsA[sub][c * 512]);
                load_lds16(Bt + (size_t)(n0 + row) * kDM + kc, &ldsB[sub][c * 512]);
            }
        }
        __syncthreads();
        #pragma unroll
        for (int sub = 0; sub < 2; ++sub) {
            bf16x8 af[4], bfr[4];
            #pragma unroll
            for (int mt = 0; mt < 4; ++mt)
                af[mt] = *(const bf16x8*)(&ldsA[sub][(wm + mt * 16 + l15) * 32 + quad * 8]);
            #pragma unroll
            for (int nt = 0; nt < 4; ++nt)
                bfr[nt] = *(const bf16x8*)(&ldsB[sub][(wn + nt * 16 + l15) * 32 + quad * 8]);
            #pragma unroll
            for (int mt = 0; mt < 4; ++mt)
                #pragma unroll
                for (int nt = 0; nt < 4; ++nt)
                    acc[mt][nt] = __builtin_amdgcn_mfma_f32_16x16x32_bf16(af[mt], bfr[nt], acc[mt][nt], 0, 0, 0);
        }
    }
    const int proj = n0 >> 11;
    void* Cb = (proj == 0) ? C0 : ((proj == 1) ? C1 : C2);
    const float scl = (proj == 0) ? scale0 : 1.0f;
    #pragma unroll
    for (int mt = 0; mt < 4; ++mt) {
        #pragma unroll
        for (int nt = 0; nt < 4; ++nt) {
            const int ng = n0 + wn + nt * 16 + l15;
            const float bv = bias[ng];
            const int col = ng & 2047;
            const int h = col >> 7, dh = col & 127;
            #pragma unroll
            for (int r = 0; r < 4; ++r) {
                const int mg = m0 + wm + mt * 16 + quad * 4 + r;
                const float val = (acc[mt][nt][r] + bv) * scl;
                if (fp32out) {
                    ((float*)Cb)[(size_t)mg * kDM + ng] = val;
                } else {
                    const int bb = mg >> 11, ss = mg & 2047;
                    ((unsigned short*)Cb)[((size_t)(bb * kNH + h) * kS + ss) * kDH + dh] = f2bf(val);
                }
            }
        }
    }
}

// ------------- causal flash attention: 128-q tiles, dbuf K/V, 1 barrier/iter ----
// Q,K: [B,H,S,Dh] bf16 (Q pre-scaled by log2e/sqrt(Dh)); Vt: [B,H,Dh,S] bf16;
// AV out: [M, DM] bf16.  Wave owns 32 q-rows (2 x 16 groups); 64 MFMA per tile.
__global__ __launch_bounds__(256, 2) void attn_kernel(
        const unsigned short* __restrict__ Q, const unsigned short* __restrict__ Kk,
        const unsigned short* __restrict__ Vt, unsigned short* __restrict__ AV) {
    __shared__ __align__(16) unsigned short ldsK[2][64 * 128];  // swizzled [key][d]
    __shared__ __align__(16) unsigned short ldsV[2][128 * 64];  // swizzled [d][key]
    __shared__ __align__(16) unsigned short ldsP[4][32 * 64];   // per-wave swizzled [q][key]
    const int bh = blockIdx.x;
    const int qt = (int)gridDim.y - 1 - (int)blockIdx.y;        // long blocks first
    const unsigned short* Qb = Q  + (size_t)bh * kS * kDH;
    const unsigned short* Kb = Kk + (size_t)bh * kS * kDH;
    const unsigned short* Vb = Vt + (size_t)bh * kDH * kS;
    const int tid = threadIdx.x, lane = tid & 63, w = tid >> 6;
    const int quad = lane >> 4, l15 = lane & 15;
    const int wq = qt * 128 + w * 32;                           // wave's first q row
    // staging offsets (source-swizzled so LDS layout is XOR-permuted; R2-verified)
    int kSrc[4], vSrc[4], ldst[4];
    #pragma unroll
    for (int i = 0; i < 4; ++i) {
        const int c = w * 4 + i;
        const int rK = c * 4 + (lane >> 4);
        const int gK = (lane & 15) ^ (rK & 15);
        kSrc[i] = rK * kDH + gK * 8;
        const int dV = c * 8 + (lane >> 3);
        const int gV = (lane & 7) ^ (dV & 7);
        vSrc[i] = dV * kS + gV * 8;
        ldst[i] = c * 512;
    }
    unsigned short* pw = ldsP[w];
    const int pswz = 2 * (l15 & 7);
    bf16x8 qf[2][4];
    #pragma unroll
    for (int qg = 0; qg < 2; ++qg)
        #pragma unroll
        for (int kk = 0; kk < 4; ++kk)
            qf[qg][kk] = *(const bf16x8*)(Qb + (size_t)(wq + qg * 16 + l15) * kDH + kk * 32 + quad * 8);
    f32x4 accO[2][8] = {};
    float mrun[2] = {-3.0e38f, -3.0e38f}, lrun[2] = {0.f, 0.f};
    const int nkt = 2 * qt + 2;
    // pre-stage tile 0 into buffer 0
    #pragma unroll
    for (int i = 0; i < 4; ++i) {
        load_lds16(Kb + kSrc[i], &ldsK[0][ldst[i]]);
        load_lds16(Vb + vSrc[i], &ldsV[0][ldst[i]]);
    }
    for (int kt = 0; kt < nkt; ++kt) {
        const int buf = kt & 1;
        __syncthreads();                       // drains prefetch issued one compute ago
        if (kt + 1 < nkt) {                    // prefetch next tile into other buffer
            const size_t ko = (size_t)(kt + 1) * (64 * kDH);
            const int vo = (kt + 1) * 64;
            #pragma unroll
            for (int i = 0; i < 4; ++i) {
                load_lds16(Kb + ko + kSrc[i], &ldsK[buf ^ 1][ldst[i]]);
                load_lds16(Vb + vo + vSrc[i], &ldsV[buf ^ 1][ldst[i]]);
            }
        }
        if (kt * 64 > wq + 31) continue;       // all keys future for this wave
        // S^T = K . Q^T : A = K-frag (m=key), B = Q-frag (n=q)
        f32x4 accS[2][4] = {};
        #pragma unroll
        for (int kk = 0; kk < 4; ++kk) {
            bf16x8 kf[4];
            #pragma unroll
            for (int mt = 0; mt < 4; ++mt)
                kf[mt] = *(const bf16x8*)(&ldsK[buf][(mt * 16 + l15) * 128 + (((kk * 4 + quad) ^ l15) << 3)]);
            #pragma unroll
            for (int qg = 0; qg < 2; ++qg)
                #pragma unroll
                for (int mt = 0; mt < 4; ++mt)
                    accS[qg][mt] = __builtin_amdgcn_mfma_f32_16x16x32_bf16(kf[mt], qf[qg][kk], accS[qg][mt], 0, 0, 0);
        }
        if (kt * 64 + 63 > wq) {               // diagonal tile: causal mask
            #pragma unroll
            for (int qg = 0; qg < 2; ++qg) {
                const int qgl = wq + qg * 16 + l15;
                #pragma unroll
                for (int mt = 0; mt < 4; ++mt)
                    #pragma unroll
                    for (int r = 0; r < 4; ++r)
                        if (kt * 64 + mt * 16 + quad * 4 + r > qgl) accS[qg][mt][r] = -3.0e38f;
            }
        }
        float al2[2];
        #pragma unroll
        for (int qg = 0; qg < 2; ++qg) {
            float mx = accS[qg][0][0];
            #pragma unroll
            for (int mt = 0; mt < 4; ++mt)
                #pragma unroll
                for (int r = 0; r < 4; ++r) mx = fmaxf(mx, accS[qg][mt][r]);
            mx = fmaxf(mx, __shfl_xor(mx, 16));
            mx = fmaxf(mx, __shfl_xor(mx, 32));
            const float mnew = fmaxf(mrun[qg], mx);
            const float al = fast_exp2(mrun[qg] - mnew);
            float rs = 0.f;
            #pragma unroll
            for (int mt = 0; mt < 4; ++mt) {
                ushort4 pk;
                unsigned short* pe = (unsigned short*)&pk;
                #pragma unroll
                for (int r = 0; r < 4; ++r) {
                    const float p = fast_exp2(accS[qg][mt][r] - mnew);
                    pe[r] = f2bf(p);
                    rs += p;
                }
                *(ushort4*)(pw + (qg * 16 + l15) * 64 + (((mt * 4 + quad) ^ pswz) << 2)) = pk;
            }
            rs += __shfl_xor(rs, 16);
            rs += __shfl_xor(rs, 32);
            lrun[qg] = lrun[qg] * al + rs;
            mrun[qg] = mnew;
            al2[qg] = al;
        }
        #pragma unroll
        for (int qg = 0; qg < 2; ++qg) {
            float albr[4];
            #pragma unroll
            for (int r = 0; r < 4; ++r)
                albr[r] = __shfl(al2[qg], (lane & 48) | (quad << 2) | r);
            #pragma unroll
            for (int dt = 0; dt < 8; ++dt)
                #pragma unroll
                for (int r = 0; r < 4; ++r)
                    accO[qg][dt][r] *= albr[r];
        }
        asm volatile("s_waitcnt lgkmcnt(0)" ::: "memory");  // P writes -> P reads (same wave)
        // O += P . V : A = P-frag (m=q), B = V-frag (n=d)
        #pragma unroll
        for (int kk = 0; kk < 2; ++kk) {
            bf16x8 pa[2];
            #pragma unroll
            for (int qg = 0; qg < 2; ++qg)
                pa[qg] = *(const bf16x8*)(pw + (qg * 16 + l15) * 64 + (((kk * 8 + quad * 2) ^ pswz) << 2));
            #pragma unroll
            for (int dt = 0; dt < 8; ++dt) {
                const bf16x8 vf = *(const bf16x8*)(&ldsV[buf][(dt * 16 + l15) * 64 + (((kk * 4 + quad) ^ (l15 & 7)) << 3)]);
                #pragma unroll
                for (int qg = 0; qg < 2; ++qg)
                    accO[qg][dt] = __builtin_amdgcn_mfma_f32_16x16x32_bf16(pa[qg], vf, accO[qg][dt], 0, 0, 0);
            }
        }
    }
    const int bb = bh >> 4, h = bh & 15;
    #pragma unroll
    for (int qg = 0; qg < 2; ++qg)
        #pragma unroll
        for (int r = 0; r < 4; ++r) {
            const float li = __shfl(lrun[qg], (lane & 48) | (quad << 2) | r);
            const float inv = 1.0f / li;
            unsigned short* orow = AV + ((size_t)bb * kS + wq + qg * 16 + quad * 4 + r) * kDM + h * kDH;
            #pragma unroll
            for (int dt = 0; dt < 8; ++dt)
                orow[dt * 16 + l15] = f2bf(accO[qg][dt][r] * inv);
        }
}

extern "C" void kernel_launch(void* const* d_in, const int* in_sizes, int n_in,
                              void* d_out, int out_size, void* d_ws, size_t ws_size,
                              hipStream_t stream) {
    const float* X   = (const float*)d_in[0];
    const float* lng = (const float*)d_in[1];
    const float* lnb = (const float*)d_in[2];
    const float* Wq  = (const float*)d_in[3];
    const float* bq  = (const float*)d_in[4];
    const float* Wk  = (const float*)d_in[5];
    const float* bk  = (const float*)d_in[6];
    const float* Wv  = (const float*)d_in[7];
    const float* bv  = (const float*)d_in[8];
    const float* Wo  = (const float*)d_in[9];
    const float* bo  = (const float*)d_in[10];
    float* out = (float*)d_out;

    char* p = (char*)d_ws;
    unsigned short* Xn  = (unsigned short*)p; p += (size_t)kM * kDM * 2;
    unsigned short* Wqt = (unsigned short*)p; p += (size_t)kDM * kDM * 2;  // Wq|Wk|Wv contiguous
    unsigned short* Wkt = (unsigned short*)p; p += (size_t)kDM * kDM * 2;
    unsigned short* Wvt = (unsigned short*)p; p += (size_t)kDM * kDM * 2;
    unsigned short* Wot = (unsigned short*)p; p += (size_t)kDM * kDM * 2;
    unsigned short* Qb  = (unsigned short*)p; p += (size_t)kM * kDM * 2;
    unsigned short* Kb  = (unsigned short*)p; p += (size_t)kM * kDM * 2;
    unsigned short* Vtb = (unsigned short*)p; p += (size_t)kM * kDM * 2;
    unsigned short* AV  = (unsigned short*)p; p += (size_t)kM * kDM * 2;
    unsigned short* Vtmp = AV;        // alias: consumed by vtr before attn writes AV
    float* biasc = (float*)Vtb;       // alias: consumed by qkv-gemm before vtr writes Vtb

    // log2(e)/sqrt(Dh): exp2-domain softmax
    const float qscale = 0.08838834764831845f * 1.4426950408889634f;

    ln_kernel<<<dim3(kM), dim3(256), 0, stream>>>(X, lng, lnb, Xn);
    wt_kernel<<<dim3(64, 64, 4), dim3(256), 0, stream>>>(Wq, Wk, Wv, Wo, Wqt, Wkt, Wvt, Wot);
    bias_pack<<<dim3(24), dim3(256), 0, stream>>>(bq, bk, bv, biasc);
    // fused QKV GEMM: N = 6144 over concatenated [Wqt|Wkt|Wvt]; m-tile fastest
    gemm_kernel<<<dim3(32, 48), dim3(256), 0, stream>>>(Xn, Wqt, biasc, Qb, Kb, Vtmp, qscale, 0);
    vtr_kernel<<<dim3(32, 2, 32), dim3(256), 0, stream>>>(Vtmp, Vtb);
    attn_kernel<<<dim3(32, 16), dim3(256), 0, stream>>>(Qb, Kb, Vtb, AV);
    gemm_kernel<<<dim3(32, 16), dim3(256), 0, stream>>>(AV, Wot, bo, out, out, out, 1.0f, 1);
}

// Round 7
// 409.974 us; speedup vs baseline: 1.0006x; 1.0006x over previous
//
#include <hip/hip_runtime.h>
#include <cstdint>

constexpr int kDM = 2048;   // d_model
constexpr int kNH = 16;     // heads
constexpr int kDH = 128;    // head dim
constexpr int kS  = 2048;   // seq
constexpr int kM  = 4096;   // B*S rows

typedef __bf16 bf16x8 __attribute__((ext_vector_type(8)));
typedef float  f32x4  __attribute__((ext_vector_type(4)));

__device__ __forceinline__ unsigned short f2bf(float f) {
    union { float f; unsigned u; } v; v.f = f;
    unsigned u = v.u;
    u += 0x7fffu + ((u >> 16) & 1u);   // RNE
    return (unsigned short)(u >> 16);
}
__device__ __forceinline__ float fast_exp2(float x) {
#if __has_builtin(__builtin_amdgcn_exp2f)
    return __builtin_amdgcn_exp2f(x);
#else
    return exp2f(x);
#endif
}
// async global->LDS, 16B per lane, LDS dest = wave-uniform base + lane*16
__device__ __forceinline__ void load_lds16(const void* g, void* l) {
    auto gp = (__attribute__((address_space(1))) unsigned int*)(uintptr_t)g;
    auto lp = (__attribute__((address_space(3))) unsigned int*)(uintptr_t)l;
    __builtin_amdgcn_global_load_lds(gp, lp, 16, 0, 0);
}

// ---------------- LayerNorm: fp32 in -> bf16 out ----------------
__global__ __launch_bounds__(256) void ln_kernel(const float* __restrict__ X,
        const float* __restrict__ g, const float* __restrict__ b,
        unsigned short* __restrict__ Xn) {
    const int row = blockIdx.x;
    const float* xr = X + (size_t)row * kDM;
    const float4 v0 = ((const float4*)xr)[threadIdx.x];
    const float4 v1 = ((const float4*)xr)[threadIdx.x + 256];
    float s  = v0.x + v0.y + v0.z + v0.w + v1.x + v1.y + v1.z + v1.w;
    float sq = v0.x*v0.x + v0.y*v0.y + v0.z*v0.z + v0.w*v0.w
             + v1.x*v1.x + v1.y*v1.y + v1.z*v1.z + v1.w*v1.w;
    #pragma unroll
    for (int m = 1; m < 64; m <<= 1) { s += __shfl_xor(s, m); sq += __shfl_xor(sq, m); }
    __shared__ float ls[4], lq[4];
    if ((threadIdx.x & 63) == 0) { ls[threadIdx.x >> 6] = s; lq[threadIdx.x >> 6] = sq; }
    __syncthreads();
    s  = ls[0] + ls[1] + ls[2] + ls[3];
    sq = lq[0] + lq[1] + lq[2] + lq[3];
    const float mu   = s * (1.0f / kDM);
    const float rstd = rsqrtf(sq * (1.0f / kDM) - mu * mu + 1e-5f);
    unsigned short* xo = Xn + (size_t)row * kDM;
    {
        const float4 gg = ((const float4*)g)[threadIdx.x];
        const float4 bb = ((const float4*)b)[threadIdx.x];
        ushort4 o;
        o.x = f2bf((v0.x - mu) * rstd * gg.x + bb.x);
        o.y = f2bf((v0.y - mu) * rstd * gg.y + bb.y);
        o.z = f2bf((v0.z - mu) * rstd * gg.z + bb.z);
        o.w = f2bf((v0.w - mu) * rstd * gg.w + bb.w);
        ((ushort4*)xo)[threadIdx.x] = o;
    }
    {
        const float4 gg = ((const float4*)g)[threadIdx.x + 256];
        const float4 bb = ((const float4*)b)[threadIdx.x + 256];
        ushort4 o;
        o.x = f2bf((v1.x - mu) * rstd * gg.x + bb.x);
        o.y = f2bf((v1.y - mu) * rstd * gg.y + bb.y);
        o.z = f2bf((v1.z - mu) * rstd * gg.z + bb.z);
        o.w = f2bf((v1.w - mu) * rstd * gg.w + bb.w);
        ((ushort4*)xo)[threadIdx.x + 256] = o;
    }
}

// ------------- weight transpose+cast: W[K][N] f32 -> Wt[N][K] bf16 -------------
__global__ __launch_bounds__(256) void wt_kernel(
        const float* __restrict__ W0, const float* __restrict__ W1,
        const float* __restrict__ W2, const float* __restrict__ W3,
        unsigned short* __restrict__ T0, unsigned short* __restrict__ T1,
        unsigned short* __restrict__ T2, unsigned short* __restrict__ T3) {
    const float* W; unsigned short* T;
    switch (blockIdx.z) {
        case 0:  W = W0; T = T0; break;
        case 1:  W = W1; T = T1; break;
        case 2:  W = W2; T = T2; break;
        default: W = W3; T = T3; break;
    }
    __shared__ float tile[32][33];
    const int tx = threadIdx.x & 31, ty = threadIdx.x >> 5;
    const int r0 = blockIdx.y * 32, c0 = blockIdx.x * 32;
    #pragma unroll
    for (int i = 0; i < 4; ++i)
        tile[ty + i * 8][tx] = W[(size_t)(r0 + ty + i * 8) * kDM + c0 + tx];
    __syncthreads();
    #pragma unroll
    for (int i = 0; i < 4; ++i)
        T[(size_t)(c0 + ty + i * 8) * kDM + r0 + tx] = f2bf(tile[tx][ty + i * 8]);
}

// --- bias concat: [bq|bk|bv] -> 6144 floats ---
__global__ __launch_bounds__(256) void bias_pack(const float* __restrict__ bq,
        const float* __restrict__ bk, const float* __restrict__ bv,
        float* __restrict__ o) {
    const int i = blockIdx.x * 256 + threadIdx.x;
    o[i] = (i < 2048) ? bq[i] : ((i < 4096) ? bk[i - 2048] : bv[i - 4096]);
}

// --- V transpose: [bh][s][dh] bf16 -> [bh][dh][s] bf16, 64x64 tiles ---
__global__ __launch_bounds__(256) void vtr_kernel(const unsigned short* __restrict__ Vin,
                                                  unsigned short* __restrict__ Vout) {
    __shared__ __align__(16) unsigned short tile[64 * 72];
    const int bhz = blockIdx.z;
    const int s0 = blockIdx.x * 64, d0 = blockIdx.y * 64;
    const int t = threadIdx.x;
    const unsigned short* src = Vin + ((size_t)bhz * kS + s0) * kDH + d0;
    #pragma unroll
    for (int i = 0; i < 2; ++i) {
        const int r = (t >> 3) + 32 * i;
        const int g = t & 7;
        *(uint4*)(tile + r * 72 + g * 8) = *(const uint4*)(src + (size_t)r * kDH + g * 8);
    }
    __syncthreads();
    unsigned short* dst = Vout + ((size_t)bhz * kDH + d0) * kS + s0;
    #pragma unroll
    for (int i = 0; i < 2; ++i) {
        const int d = (t >> 3) + 32 * i;
        const int sg = t & 7;
        union { unsigned short u[8]; uint4 v; } o;
        #pragma unroll
        for (int j = 0; j < 8; ++j)
            o.u[j] = tile[(sg * 8 + j) * 72 + d];
        *(uint4*)(dst + (size_t)d * kS + sg * 8) = o.v;
    }
}

// ------------- GEMM: C = A[M,K]bf16 @ Bt[N,K]^T bf16 + bias -------------
// BK=64 via two 32-k sub-buffers; ascending-contiguous staging (R4: source
// swizzle breaks VMEM coalescing).  blockIdx.x = m-tile (fastest).
__global__ __launch_bounds__(256) void gemm_kernel(
        const unsigned short* __restrict__ A, const unsigned short* __restrict__ Bt,
        const float* __restrict__ bias, void* __restrict__ C0, void* __restrict__ C1,
        void* __restrict__ C2, const float scale0, const int fp32out) {
    __shared__ __align__(16) unsigned short ldsA[2][128 * 32];
    __shared__ __align__(16) unsigned short ldsB[2][128 * 32];
    const int m0 = blockIdx.x * 128, n0 = blockIdx.y * 128;
    const int tid = threadIdx.x, lane = tid & 63, w = tid >> 6;
    const int wm = (w >> 1) * 64, wn = (w & 1) * 64;
    const int quad = lane >> 4, l15 = lane & 15;
    f32x4 acc[4][4] = {};
    const int srow = lane >> 2, scol = (lane & 3) * 8;
    for (int k0 = 0; k0 < kDM; k0 += 64) {
        __syncthreads();
        #pragma unroll
        for (int sub = 0; sub < 2; ++sub) {
            #pragma unroll
            for (int i = 0; i < 2; ++i) {
                const int c = w + i * 4;
                const int row = c * 16 + srow;
                const int kc = k0 + sub * 32 + scol;
                load_lds16(A  + (size_t)(m0 + row) * kDM + kc, &ldsA[sub][c * 512]);
                load_lds16(Bt + (size_t)(n0 + row) * kDM + kc, &ldsB[sub][c * 512]);
            }
        }
        __syncthreads();
        #pragma unroll
        for (int sub = 0; sub < 2; ++sub) {
            bf16x8 af[4], bfr[4];
            #pragma unroll
            for (int mt = 0; mt < 4; ++mt)
                af[mt] = *(const bf16x8*)(&ldsA[sub][(wm + mt * 16 + l15) * 32 + quad * 8]);
            #pragma unroll
            for (int nt = 0; nt < 4; ++nt)
                bfr[nt] = *(const bf16x8*)(&ldsB[sub][(wn + nt * 16 + l15) * 32 + quad * 8]);
            #pragma unroll
            for (int mt = 0; mt < 4; ++mt)
                #pragma unroll
                for (int nt = 0; nt < 4; ++nt)
                    acc[mt][nt] = __builtin_amdgcn_mfma_f32_16x16x32_bf16(af[mt], bfr[nt], acc[mt][nt], 0, 0, 0);
        }
    }
    const int proj = n0 >> 11;
    void* Cb = (proj == 0) ? C0 : ((proj == 1) ? C1 : C2);
    const float scl = (proj == 0) ? scale0 : 1.0f;
    #pragma unroll
    for (int mt = 0; mt < 4; ++mt) {
        #pragma unroll
        for (int nt = 0; nt < 4; ++nt) {
            const int ng = n0 + wn + nt * 16 + l15;
            const float bv = bias[ng];
            const int col = ng & 2047;
            const int h = col >> 7, dh = col & 127;
            #pragma unroll
            for (int r = 0; r < 4; ++r) {
                const int mg = m0 + wm + mt * 16 + quad * 4 + r;
                const float val = (acc[mt][nt][r] + bv) * scl;
                if (fp32out) {
                    ((float*)Cb)[(size_t)mg * kDM + ng] = val;
                } else {
                    const int bb = mg >> 11, ss = mg & 2047;
                    ((unsigned short*)Cb)[((size_t)(bb * kNH + h) * kS + ss) * kDH + dh] = f2bf(val);
                }
            }
        }
    }
}

// ------- causal flash attention: 128-q tiles, single-buffer K/V, 48 KB LDS -------
// Q,K: [B,H,S,Dh] bf16 (Q pre-scaled by log2e/sqrt(Dh)); Vt: [B,H,Dh,S] bf16;
// AV out: [M, DM] bf16.  Wave owns 32 q-rows; 64 MFMA per key-tile iteration.
// y->qt mapping balances per-CU work: qt = y<8 ? 15-y : y-8 (long+short co-resident).
__global__ __launch_bounds__(256, 2) void attn_kernel(
        const unsigned short* __restrict__ Q, const unsigned short* __restrict__ Kk,
        const unsigned short* __restrict__ Vt, unsigned short* __restrict__ AV) {
    __shared__ __align__(16) unsigned short ldsK[64 * 128];   // swizzled [key][d]
    __shared__ __align__(16) unsigned short ldsV[128 * 64];   // swizzled [d][key]
    __shared__ __align__(16) unsigned short ldsP[4][32 * 64]; // per-wave swizzled [q][key]
    const int bh = blockIdx.x;
    const int y = blockIdx.y;
    const int qt = (y < 8) ? (15 - y) : (y - 8);
    const unsigned short* Qb = Q  + (size_t)bh * kS * kDH;
    const unsigned short* Kb = Kk + (size_t)bh * kS * kDH;
    const unsigned short* Vb = Vt + (size_t)bh * kDH * kS;
    const int tid = threadIdx.x, lane = tid & 63, w = tid >> 6;
    const int quad = lane >> 4, l15 = lane & 15;
    const int wq = qt * 128 + w * 32;                         // wave's first q row
    // staging offsets (source-swizzled so LDS layout is XOR-permuted; R2-verified)
    int kSrc[4], vSrc[4], ldst[4];
    #pragma unroll
    for (int i = 0; i < 4; ++i) {
        const int c = w * 4 + i;
        const int rK = c * 4 + (lane >> 4);
        const int gK = (lane & 15) ^ (rK & 15);
        kSrc[i] = rK * kDH + gK * 8;
        const int dV = c * 8 + (lane >> 3);
        const int gV = (lane & 7) ^ (dV & 7);
        vSrc[i] = dV * kS + gV * 8;
        ldst[i] = c * 512;
    }
    unsigned short* pw = ldsP[w];
    const int pswz = 2 * (l15 & 7);
    bf16x8 qf[2][4];
    #pragma unroll
    for (int qg = 0; qg < 2; ++qg)
        #pragma unroll
        for (int kk = 0; kk < 4; ++kk)
            qf[qg][kk] = *(const bf16x8*)(Qb + (size_t)(wq + qg * 16 + l15) * kDH + kk * 32 + quad * 8);
    f32x4 accO[2][8] = {};
    float mrun[2] = {-3.0e38f, -3.0e38f}, lrun[2] = {0.f, 0.f};
    const int nkt = 2 * qt + 2;
    for (int kt = 0; kt < nkt; ++kt) {
        __syncthreads();
        {
            const size_t ko = (size_t)kt * (64 * kDH);
            const int vo = kt * 64;
            #pragma unroll
            for (int i = 0; i < 4; ++i) {
                load_lds16(Kb + ko + kSrc[i], ldsK + ldst[i]);
                load_lds16(Vb + vo + vSrc[i], ldsV + ldst[i]);
            }
        }
        __syncthreads();
        if (kt * 64 > wq + 31) continue;       // all keys future for this wave
        // S^T = K . Q^T : A = K-frag (m=key), B = Q-frag (n=q)
        f32x4 accS[2][4] = {};
        #pragma unroll
        for (int kk = 0; kk < 4; ++kk) {
            bf16x8 kf[4];
            #pragma unroll
            for (int mt = 0; mt < 4; ++mt)
                kf[mt] = *(const bf16x8*)(ldsK + (mt * 16 + l15) * 128 + (((kk * 4 + quad) ^ l15) << 3));
            #pragma unroll
            for (int qg = 0; qg < 2; ++qg)
                #pragma unroll
                for (int mt = 0; mt < 4; ++mt)
                    accS[qg][mt] = __builtin_amdgcn_mfma_f32_16x16x32_bf16(kf[mt], qf[qg][kk], accS[qg][mt], 0, 0, 0);
        }
        if (kt * 64 + 63 > wq) {               // diagonal tile: causal mask
            #pragma unroll
            for (int qg = 0; qg < 2; ++qg) {
                const int qgl = wq + qg * 16 + l15;
                #pragma unroll
                for (int mt = 0; mt < 4; ++mt)
                    #pragma unroll
                    for (int r = 0; r < 4; ++r)
                        if (kt * 64 + mt * 16 + quad * 4 + r > qgl) accS[qg][mt][r] = -3.0e38f;
            }
        }
        float al2[2];
        #pragma unroll
        for (int qg = 0; qg < 2; ++qg) {
            float mx = accS[qg][0][0];
            #pragma unroll
            for (int mt = 0; mt < 4; ++mt)
                #pragma unroll
                for (int r = 0; r < 4; ++r) mx = fmaxf(mx, accS[qg][mt][r]);
            mx = fmaxf(mx, __shfl_xor(mx, 16));
            mx = fmaxf(mx, __shfl_xor(mx, 32));
            const float mnew = fmaxf(mrun[qg], mx);
            const float al = fast_exp2(mrun[qg] - mnew);
            float rs = 0.f;
            #pragma unroll
            for (int mt = 0; mt < 4; ++mt) {
                ushort4 pk;
                unsigned short* pe = (unsigned short*)&pk;
                #pragma unroll
                for (int r = 0; r < 4; ++r) {
                    const float p = fast_exp2(accS[qg][mt][r] - mnew);
                    pe[r] = f2bf(p);
                    rs += p;
                }
                *(ushort4*)(pw + (qg * 16 + l15) * 64 + (((mt * 4 + quad) ^ pswz) << 2)) = pk;
            }
            rs += __shfl_xor(rs, 16);
            rs += __shfl_xor(rs, 32);
            lrun[qg] = lrun[qg] * al + rs;
            mrun[qg] = mnew;
            al2[qg] = al;
        }
        #pragma unroll
        for (int qg = 0; qg < 2; ++qg) {
            float albr[4];
            #pragma unroll
            for (int r = 0; r < 4; ++r)
                albr[r] = __shfl(al2[qg], (lane & 48) | (quad << 2) | r);
            #pragma unroll
            for (int dt = 0; dt < 8; ++dt)
                #pragma unroll
                for (int r = 0; r < 4; ++r)
                    accO[qg][dt][r] *= albr[r];
        }
        asm volatile("s_waitcnt lgkmcnt(0)" ::: "memory");  // P writes -> P reads (same wave)
        // O += P . V : A = P-frag (m=q), B = V-frag (n=d)
        #pragma unroll
        for (int kk = 0; kk < 2; ++kk) {
            bf16x8 pa[2];
            #pragma unroll
            for (int qg = 0; qg < 2; ++qg)
                pa[qg] = *(const bf16x8*)(pw + (qg * 16 + l15) * 64 + (((kk * 8 + quad * 2) ^ pswz) << 2));
            #pragma unroll
            for (int dt = 0; dt < 8; ++dt) {
                const bf16x8 vf = *(const bf16x8*)(ldsV + (dt * 16 + l15) * 64 + (((kk * 4 + quad) ^ (l15 & 7)) << 3));
                #pragma unroll
                for (int qg = 0; qg < 2; ++qg)
                    accO[qg][dt] = __builtin_amdgcn_mfma_f32_16x16x32_bf16(pa[qg], vf, accO[qg][dt], 0, 0, 0);
            }
        }
    }
    const int bb = bh >> 4, h = bh & 15;
    #pragma unroll
    for (int qg = 0; qg < 2; ++qg)
        #pragma unroll
        for (int r = 0; r < 4; ++r) {
            const float li = __shfl(lrun[qg], (lane & 48) | (quad << 2) | r);
            const float inv = 1.0f / li;
            unsigned short* orow = AV + ((size_t)bb * kS + wq + qg * 16 + quad * 4 + r) * kDM + h * kDH;
            #pragma unroll
            for (int dt = 0; dt < 8; ++dt)
                orow[dt * 16 + l15] = f2bf(accO[qg][dt][r] * inv);
        }
}

extern "C" void kernel_launch(void* const* d_in, const int* in_sizes, int n_in,
                              void* d_out, int out_size, void* d_ws, size_t ws_size,
                              hipStream_t stream) {
    const float* X   = (const float*)d_in[0];
    const float* lng = (const float*)d_in[1];
    const float* lnb = (const float*)d_in[2];
    const float* Wq  = (const float*)d_in[3];
    const float* bq  = (const float*)d_in[4];
    const float* Wk  = (const float*)d_in[5];
    const float* bk  = (const float*)d_in[6];
    const float* Wv  = (const float*)d_in[7];
    const float* bv  = (const float*)d_in[8];
    const float* Wo  = (const float*)d_in[9];
    const float* bo  = (const float*)d_in[10];
    float* out = (float*)d_out;

    char* p = (char*)d_ws;
    unsigned short* Xn  = (unsigned short*)p; p += (size_t)kM * kDM * 2;
    unsigned short* Wqt = (unsigned short*)p; p += (size_t)kDM * kDM * 2;  // Wq|Wk|Wv contiguous
    unsigned short* Wkt = (unsigned short*)p; p += (size_t)kDM * kDM * 2;
    unsigned short* Wvt = (unsigned short*)p; p += (size_t)kDM * kDM * 2;
    unsigned short* Wot = (unsigned short*)p; p += (size_t)kDM * kDM * 2;
    unsigned short* Qb  = (unsigned short*)p; p += (size_t)kM * kDM * 2;
    unsigned short* Kb  = (unsigned short*)p; p += (size_t)kM * kDM * 2;
    unsigned short* Vtb = (unsigned short*)p; p += (size_t)kM * kDM * 2;
    unsigned short* AV  = (unsigned short*)p; p += (size_t)kM * kDM * 2;
    unsigned short* Vtmp = AV;        // alias: consumed by vtr before attn writes AV
    float* biasc = (float*)Vtb;       // alias: consumed by qkv-gemm before vtr writes Vtb

    // log2(e)/sqrt(Dh): exp2-domain softmax
    const float qscale = 0.08838834764831845f * 1.4426950408889634f;

    ln_kernel<<<dim3(kM), dim3(256), 0, stream>>>(X, lng, lnb, Xn);
    wt_kernel<<<dim3(64, 64, 4), dim3(256), 0, stream>>>(Wq, Wk, Wv, Wo, Wqt, Wkt, Wvt, Wot);
    bias_pack<<<dim3(24), dim3(256), 0, stream>>>(bq, bk, bv, biasc);
    // fused QKV GEMM: N = 6144 over concatenated [Wqt|Wkt|Wvt]; m-tile fastest
    gemm_kernel<<<dim3(32, 48), dim3(256), 0, stream>>>(Xn, Wqt, biasc, Qb, Kb, Vtmp, qscale, 0);
    vtr_kernel<<<dim3(32, 2, 32), dim3(256), 0, stream>>>(Vtmp, Vtb);
    attn_kernel<<<dim3(32, 16), dim3(256), 0, stream>>>(Qb, Kb, Vtb, AV);
    gemm_kernel<<<dim3(32, 16), dim3(256), 0, stream>>>(AV, Wot, bo, out, out, out, 1.0f, 1);
}

// Round 9
// 407.631 us; speedup vs baseline: 1.0063x; 1.0057x over previous
//
#include <hip/hip_runtime.h>
#include <cstdint>

constexpr int kDM = 2048;   // d_model
constexpr int kNH = 16;     // heads
constexpr int kDH = 128;    // head dim
constexpr int kS  = 2048;   // seq
constexpr int kM  = 4096;   // B*S rows

typedef __bf16 bf16x8 __attribute__((ext_vector_type(8)));
typedef float  f32x4  __attribute__((ext_vector_type(4)));

__device__ __forceinline__ unsigned short f2bf(float f) {
    union { float f; unsigned u; } v; v.f = f;
    unsigned u = v.u;
    u += 0x7fffu + ((u >> 16) & 1u);   // RNE
    return (unsigned short)(u >> 16);
}
__device__ __forceinline__ float bf2f(unsigned short b) {
    union { unsigned u; float f; } v; v.u = ((unsigned)b) << 16;
    return v.f;
}
__device__ __forceinline__ float fast_exp2(float x) {
#if __has_builtin(__builtin_amdgcn_exp2f)
    return __builtin_amdgcn_exp2f(x);
#else
    return exp2f(x);
#endif
}
// async global->LDS, 16B per lane, LDS dest = wave-uniform base + lane*16
__device__ __forceinline__ void load_lds16(const void* g, void* l) {
    auto gp = (__attribute__((address_space(1))) unsigned int*)(uintptr_t)g;
    auto lp = (__attribute__((address_space(3))) unsigned int*)(uintptr_t)l;
    __builtin_amdgcn_global_load_lds(gp, lp, 16, 0, 0);
}

// ---------------- LayerNorm: fp32 in -> bf16 out ----------------
__global__ __launch_bounds__(256) void ln_kernel(const float* __restrict__ X,
        const float* __restrict__ g, const float* __restrict__ b,
        unsigned short* __restrict__ Xn) {
    const int row = blockIdx.x;
    const float* xr = X + (size_t)row * kDM;
    const float4 v0 = ((const float4*)xr)[threadIdx.x];
    const float4 v1 = ((const float4*)xr)[threadIdx.x + 256];
    float s  = v0.x + v0.y + v0.z + v0.w + v1.x + v1.y + v1.z + v1.w;
    float sq = v0.x*v0.x + v0.y*v0.y + v0.z*v0.z + v0.w*v0.w
             + v1.x*v1.x + v1.y*v1.y + v1.z*v1.z + v1.w*v1.w;
    #pragma unroll
    for (int m = 1; m < 64; m <<= 1) { s += __shfl_xor(s, m); sq += __shfl_xor(sq, m); }
    __shared__ float ls[4], lq[4];
    if ((threadIdx.x & 63) == 0) { ls[threadIdx.x >> 6] = s; lq[threadIdx.x >> 6] = sq; }
    __syncthreads();
    s  = ls[0] + ls[1] + ls[2] + ls[3];
    sq = lq[0] + lq[1] + lq[2] + lq[3];
    const float mu   = s * (1.0f / kDM);
    const float rstd = rsqrtf(sq * (1.0f / kDM) - mu * mu + 1e-5f);
    unsigned short* xo = Xn + (size_t)row * kDM;
    {
        const float4 gg = ((const float4*)g)[threadIdx.x];
        const float4 bb = ((const float4*)b)[threadIdx.x];
        ushort4 o;
        o.x = f2bf((v0.x - mu) * rstd * gg.x + bb.x);
        o.y = f2bf((v0.y - mu) * rstd * gg.y + bb.y);
        o.z = f2bf((v0.z - mu) * rstd * gg.z + bb.z);
        o.w = f2bf((v0.w - mu) * rstd * gg.w + bb.w);
        ((ushort4*)xo)[threadIdx.x] = o;
    }
    {
        const float4 gg = ((const float4*)g)[threadIdx.x + 256];
        const float4 bb = ((const float4*)b)[threadIdx.x + 256];
        ushort4 o;
        o.x = f2bf((v1.x - mu) * rstd * gg.x + bb.x);
        o.y = f2bf((v1.y - mu) * rstd * gg.y + bb.y);
        o.z = f2bf((v1.z - mu) * rstd * gg.z + bb.z);
        o.w = f2bf((v1.w - mu) * rstd * gg.w + bb.w);
        ((ushort4*)xo)[threadIdx.x + 256] = o;
    }
}

// ------------- weight transpose+cast: W[K][N] f32 -> Wt[N][K] bf16 -------------
__global__ __launch_bounds__(256) void wt_kernel(
        const float* __restrict__ W0, const float* __restrict__ W1,
        const float* __restrict__ W2, const float* __restrict__ W3,
        unsigned short* __restrict__ T0, unsigned short* __restrict__ T1,
        unsigned short* __restrict__ T2, unsigned short* __restrict__ T3) {
    const float* W; unsigned short* T;
    switch (blockIdx.z) {
        case 0:  W = W0; T = T0; break;
        case 1:  W = W1; T = T1; break;
        case 2:  W = W2; T = T2; break;
        default: W = W3; T = T3; break;
    }
    __shared__ float tile[32][33];
    const int tx = threadIdx.x & 31, ty = threadIdx.x >> 5;
    const int r0 = blockIdx.y * 32, c0 = blockIdx.x * 32;
    #pragma unroll
    for (int i = 0; i < 4; ++i)
        tile[ty + i * 8][tx] = W[(size_t)(r0 + ty + i * 8) * kDM + c0 + tx];
    __syncthreads();
    #pragma unroll
    for (int i = 0; i < 4; ++i)
        T[(size_t)(c0 + ty + i * 8) * kDM + r0 + tx] = f2bf(tile[tx][ty + i * 8]);
}

// --- bias concat: [bq|bk|bv] -> 6144 floats ---
__global__ __launch_bounds__(256) void bias_pack(const float* __restrict__ bq,
        const float* __restrict__ bk, const float* __restrict__ bv,
        float* __restrict__ o) {
    const int i = blockIdx.x * 256 + threadIdx.x;
    o[i] = (i < 2048) ? bq[i] : ((i < 4096) ? bk[i - 2048] : bv[i - 4096]);
}

// --- V transpose: [bh][s][dh] bf16 -> [bh][dh][s] bf16, 64x64 tiles ---
__global__ __launch_bounds__(256) void vtr_kernel(const unsigned short* __restrict__ Vin,
                                                  unsigned short* __restrict__ Vout) {
    __shared__ __align__(16) unsigned short tile[64 * 72];
    const int bhz = blockIdx.z;
    const int s0 = blockIdx.x * 64, d0 = blockIdx.y * 64;
    const int t = threadIdx.x;
    const unsigned short* src = Vin + ((size_t)bhz * kS + s0) * kDH + d0;
    #pragma unroll
    for (int i = 0; i < 2; ++i) {
        const int r = (t >> 3) + 32 * i;
        const int g = t & 7;
        *(uint4*)(tile + r * 72 + g * 8) = *(const uint4*)(src + (size_t)r * kDH + g * 8);
    }
    __syncthreads();
    unsigned short* dst = Vout + ((size_t)bhz * kDH + d0) * kS + s0;
    #pragma unroll
    for (int i = 0; i < 2; ++i) {
        const int d = (t >> 3) + 32 * i;
        const int sg = t & 7;
        union { unsigned short u[8]; uint4 v; } o;
        #pragma unroll
        for (int j = 0; j < 8; ++j)
            o.u[j] = tile[(sg * 8 + j) * 72 + d];
        *(uint4*)(dst + (size_t)d * kS + sg * 8) = o.v;
    }
}

// ------------- GEMM: C = A[M,K]bf16 @ Bt[N,K]^T bf16 + bias -------------
// BK=64 via two 32-k sub-buffers; ascending-contiguous staging (R4: source
// swizzle breaks VMEM coalescing).  blockIdx.x = m-tile (fastest).
__global__ __launch_bounds__(256) void gemm_kernel(
        const unsigned short* __restrict__ A, const unsigned short* __restrict__ Bt,
        const float* __restrict__ bias, void* __restrict__ C0, void* __restrict__ C1,
        void* __restrict__ C2, const float scale0, const int fp32out) {
    __shared__ __align__(16) unsigned short ldsA[2][128 * 32];
    __shared__ __align__(16) unsigned short ldsB[2][128 * 32];
    const int m0 = blockIdx.x * 128, n0 = blockIdx.y * 128;
    const int tid = threadIdx.x, lane = tid & 63, w = tid >> 6;
    const int wm = (w >> 1) * 64, wn = (w & 1) * 64;
    const int quad = lane >> 4, l15 = lane & 15;
    f32x4 acc[4][4] = {};
    const int srow = lane >> 2, scol = (lane & 3) * 8;
    for (int k0 = 0; k0 < kDM; k0 += 64) {
        __syncthreads();
        #pragma unroll
        for (int sub = 0; sub < 2; ++sub) {
            #pragma unroll
            for (int i = 0; i < 2; ++i) {
                const int c = w + i * 4;
                const int row = c * 16 + srow;
                const int kc = k0 + sub * 32 + scol;
                load_lds16(A  + (size_t)(m0 + row) * kDM + kc, &ldsA[sub][c * 512]);
                load_lds16(Bt + (size_t)(n0 + row) * kDM + kc, &ldsB[sub][c * 512]);
            }
        }
        __syncthreads();
        #pragma unroll
        for (int sub = 0; sub < 2; ++sub) {
            bf16x8 af[4], bfr[4];
            #pragma unroll
            for (int mt = 0; mt < 4; ++mt)
                af[mt] = *(const bf16x8*)(&ldsA[sub][(wm + mt * 16 + l15) * 32 + quad * 8]);
            #pragma unroll
            for (int nt = 0; nt < 4; ++nt)
                bfr[nt] = *(const bf16x8*)(&ldsB[sub][(wn + nt * 16 + l15) * 32 + quad * 8]);
            #pragma unroll
            for (int mt = 0; mt < 4; ++mt)
                #pragma unroll
                for (int nt = 0; nt < 4; ++nt)
                    acc[mt][nt] = __builtin_amdgcn_mfma_f32_16x16x32_bf16(af[mt], bfr[nt], acc[mt][nt], 0, 0, 0);
        }
    }
    const int proj = n0 >> 11;
    void* Cb = (proj == 0) ? C0 : ((proj == 1) ? C1 : C2);
    const float scl = (proj == 0) ? scale0 : 1.0f;
    #pragma unroll
    for (int mt = 0; mt < 4; ++mt) {
        #pragma unroll
        for (int nt = 0; nt < 4; ++nt) {
            const int ng = n0 + wn + nt * 16 + l15;
            const float bv = bias[ng];
            const int col = ng & 2047;
            const int h = col >> 7, dh = col & 127;
            #pragma unroll
            for (int r = 0; r < 4; ++r) {
                const int mg = m0 + wm + mt * 16 + quad * 4 + r;
                const float val = (acc[mt][nt][r] + bv) * scl;
                if (fp32out) {
                    ((float*)Cb)[(size_t)mg * kDM + ng] = val;
                } else {
                    const int bb = mg >> 11, ss = mg & 2047;
                    ((unsigned short*)Cb)[((size_t)(bb * kNH + h) * kS + ss) * kDH + dh] = f2bf(val);
                }
            }
        }
    }
}

// ------------- split-K GEMM (Wo): z-slice computes K range, fp32 partial out ----
__global__ __launch_bounds__(256) void gemm_splitk(
        const unsigned short* __restrict__ A, const unsigned short* __restrict__ Bt,
        float* __restrict__ P0, float* __restrict__ P1) {
    __shared__ __align__(16) unsigned short ldsA[2][128 * 32];
    __shared__ __align__(16) unsigned short ldsB[2][128 * 32];
    const int m0 = blockIdx.x * 128, n0 = blockIdx.y * 128;
    const int kbeg = blockIdx.z * 1024;
    float* P = blockIdx.z ? P1 : P0;
    const int tid = threadIdx.x, lane = tid & 63, w = tid >> 6;
    const int wm = (w >> 1) * 64, wn = (w & 1) * 64;
    const int quad = lane >> 4, l15 = lane & 15;
    f32x4 acc[4][4] = {};
    const int srow = lane >> 2, scol = (lane & 3) * 8;
    for (int k0 = kbeg; k0 < kbeg + 1024; k0 += 64) {
        __syncthreads();
        #pragma unroll
        for (int sub = 0; sub < 2; ++sub) {
            #pragma unroll
            for (int i = 0; i < 2; ++i) {
                const int c = w + i * 4;
                const int row = c * 16 + srow;
                const int kc = k0 + sub * 32 + scol;
                load_lds16(A  + (size_t)(m0 + row) * kDM + kc, &ldsA[sub][c * 512]);
                load_lds16(Bt + (size_t)(n0 + row) * kDM + kc, &ldsB[sub][c * 512]);
            }
        }
        __syncthreads();
        #pragma unroll
        for (int sub = 0; sub < 2; ++sub) {
            bf16x8 af[4], bfr[4];
            #pragma unroll
            for (int mt = 0; mt < 4; ++mt)
                af[mt] = *(const bf16x8*)(&ldsA[sub][(wm + mt * 16 + l15) * 32 + quad * 8]);
            #pragma unroll
            for (int nt = 0; nt < 4; ++nt)
                bfr[nt] = *(const bf16x8*)(&ldsB[sub][(wn + nt * 16 + l15) * 32 + quad * 8]);
            #pragma unroll
            for (int mt = 0; mt < 4; ++mt)
                #pragma unroll
                for (int nt = 0; nt < 4; ++nt)
                    acc[mt][nt] = __builtin_amdgcn_mfma_f32_16x16x32_bf16(af[mt], bfr[nt], acc[mt][nt], 0, 0, 0);
        }
    }
    #pragma unroll
    for (int mt = 0; mt < 4; ++mt)
        #pragma unroll
        for (int nt = 0; nt < 4; ++nt) {
            const int ng = n0 + wn + nt * 16 + l15;
            #pragma unroll
            for (int r = 0; r < 4; ++r) {
                const int mg = m0 + wm + mt * 16 + quad * 4 + r;
                P[(size_t)mg * kDM + ng] = acc[mt][nt][r];
            }
        }
}

// --- split-K reduce: out = P0 + P1 + bias ---
__global__ __launch_bounds__(256) void wo_reduce(const float* __restrict__ P0,
        const float* __restrict__ P1, const float* __restrict__ bias,
        float* __restrict__ out) {
    const int i = blockIdx.x * 256 + threadIdx.x;   // float4 index, kM*kDM/4 total
    const float4 a = ((const float4*)P0)[i];
    const float4 b = ((const float4*)P1)[i];
    const float4 bv = ((const float4*)bias)[i & 511];
    float4 o;
    o.x = a.x + b.x + bv.x;
    o.y = a.y + b.y + bv.y;
    o.z = a.z + b.z + bv.z;
    o.w = a.w + b.w + bv.w;
    ((float4*)out)[i] = o;
}

// ------------- causal flash attention, S^T form, paired q-tiles (R5-exact) -------
// Q,K: [B,H,S,Dh] bf16 (Q pre-scaled by log2e/sqrt(Dh)); Vt: [B,H,Dh,S] bf16;
// AV out: [M, DM] bf16.  Block handles q-tiles pr and 31-pr (uniform 33 key-iters).
__global__ __launch_bounds__(256, 2) void attn_kernel(
        const unsigned short* __restrict__ Q, const unsigned short* __restrict__ Kk,
        const unsigned short* __restrict__ Vt, unsigned short* __restrict__ AV) {
    __shared__ __align__(16) unsigned short ldsK[64 * 128];   // swizzled [key][d]
    __shared__ __align__(16) unsigned short ldsV[128 * 64];   // swizzled [d][key]
    __shared__ __align__(16) unsigned short ldsP[4 * 16 * 64];// per-wave swizzled [q][key]
    const int bh = blockIdx.x, pr = blockIdx.y;
    const unsigned short* Qb = Q  + (size_t)bh * kS * kDH;
    const unsigned short* Kb = Kk + (size_t)bh * kS * kDH;
    const unsigned short* Vb = Vt + (size_t)bh * kDH * kS;
    const int tid = threadIdx.x, lane = tid & 63, w = tid >> 6;
    const int quad = lane >> 4, l15 = lane & 15;
    int kSrc[4], vSrc[4], ldst[4];
    #pragma unroll
    for (int i = 0; i < 4; ++i) {
        const int c = w * 4 + i;
        const int rK = c * 4 + (lane >> 4);
        const int gK = (lane & 15) ^ (rK & 15);
        kSrc[i] = rK * kDH + gK * 8;
        const int dV = c * 8 + (lane >> 3);
        const int gV = (lane & 7) ^ (dV & 7);
        vSrc[i] = dV * kS + gV * 8;
        ldst[i] = c * 512;
    }
    unsigned short* pw = ldsP + w * 1024;
    const int pswz = 2 * (l15 & 7);           // even XOR keeps 16B pairs intact
    const int bb = bh >> 4, h = bh & 15;
    for (int half = 0; half < 2; ++half) {
        const int qt = half ? (31 - pr) : pr;
        const int qrow0 = qt * 64 + w * 16;   // wave owns 16 q-rows
        bf16x8 qf[4];
        #pragma unroll
        for (int kk = 0; kk < 4; ++kk)
            qf[kk] = *(const bf16x8*)(Qb + (size_t)(qrow0 + l15) * kDH + kk * 32 + quad * 8);
        f32x4 accO[8] = {};
        float mrun = -3.0e38f, lrun = 0.0f;   // per-lane state for q = qrow0 + l15
        for (int kt = 0; kt <= qt; ++kt) {
            __syncthreads();
            #pragma unroll
            for (int i = 0; i < 4; ++i) {
                load_lds16(Kb + (size_t)kt * (64 * kDH) + kSrc[i], ldsK + ldst[i]);
                load_lds16(Vb + kt * 64 + vSrc[i], ldsV + ldst[i]);
            }
            __syncthreads();
            // S^T = K . Q^T : A = K-frag (m=key), B = Q-frag (n=q)
            f32x4 accS[4] = {};
            #pragma unroll
            for (int kk = 0; kk < 4; ++kk) {
                bf16x8 kf[4];
                #pragma unroll
                for (int mt = 0; mt < 4; ++mt)
                    kf[mt] = *(const bf16x8*)(ldsK + (mt * 16 + l15) * 128 + (((kk * 4 + quad) ^ l15) << 3));
                #pragma unroll
                for (int mt = 0; mt < 4; ++mt)
                    accS[mt] = __builtin_amdgcn_mfma_f32_16x16x32_bf16(kf[mt], qf[kk], accS[mt], 0, 0, 0);
            }
            if (kt == qt) {                   // diagonal: mask key_local > q_local
                const int ql = w * 16 + l15;
                #pragma unroll
                for (int mt = 0; mt < 4; ++mt)
                    #pragma unroll
                    for (int r = 0; r < 4; ++r)
                        if (mt * 16 + quad * 4 + r > ql) accS[mt][r] = -3.0e38f;
            }
            // per-lane softmax over 16 in-register keys + 2 cross-quad shuffles
            float mx = accS[0][0];
            #pragma unroll
            for (int mt = 0; mt < 4; ++mt)
                #pragma unroll
                for (int r = 0; r < 4; ++r) mx = fmaxf(mx, accS[mt][r]);
            mx = fmaxf(mx, __shfl_xor(mx, 16));
            mx = fmaxf(mx, __shfl_xor(mx, 32));
            const float mnew = fmaxf(mrun, mx);
            const float al = fast_exp2(mrun - mnew);
            float rs = 0.f;
            #pragma unroll
            for (int mt = 0; mt < 4; ++mt) {
                ushort4 pk;
                unsigned short* pe = (unsigned short*)&pk;
                #pragma unroll
                for (int r = 0; r < 4; ++r) {
                    const float p = fast_exp2(accS[mt][r] - mnew);
                    const unsigned short pb = f2bf(p);
                    pe[r] = pb;
                    rs += bf2f(pb);           // keep l consistent with bf16 P
                }
                *(ushort4*)(pw + l15 * 64 + (((mt * 4 + quad) ^ pswz) << 2)) = pk;
            }
            rs += __shfl_xor(rs, 16);
            rs += __shfl_xor(rs, 32);
            lrun = lrun * al + rs;
            mrun = mnew;
            float albr[4];
            #pragma unroll
            for (int r = 0; r < 4; ++r)
                albr[r] = __shfl(al, (lane & 48) | (quad << 2) | r);
            #pragma unroll
            for (int dt = 0; dt < 8; ++dt)
                #pragma unroll
                for (int r = 0; r < 4; ++r)
                    accO[dt][r] *= albr[r];
            asm volatile("s_waitcnt lgkmcnt(0)" ::: "memory");  // P writes visible to own wave
            // O += P . V : A = P-frag (m=q), B = V-frag (n=d)
            #pragma unroll
            for (int kk = 0; kk < 2; ++kk) {
                const bf16x8 pa = *(const bf16x8*)(pw + l15 * 64 + (((kk * 8 + quad * 2) ^ pswz) << 2));
                #pragma unroll
                for (int dt = 0; dt < 8; ++dt) {
                    const bf16x8 vf = *(const bf16x8*)(ldsV + (dt * 16 + l15) * 64 + (((kk * 4 + quad) ^ (l15 & 7)) << 3));
                    accO[dt] = __builtin_amdgcn_mfma_f32_16x16x32_bf16(pa, vf, accO[dt], 0, 0, 0);
                }
            }
        }
        float linv[4];
        #pragma unroll
        for (int r = 0; r < 4; ++r)
            linv[r] = __shfl(lrun, (lane & 48) | (quad << 2) | r);
        #pragma unroll
        for (int r = 0; r < 4; ++r) {
            const float inv = 1.0f / linv[r];
            unsigned short* orow = AV + ((size_t)bb * kS + qrow0 + quad * 4 + r) * kDM + h * kDH;
            #pragma unroll
            for (int dt = 0; dt < 8; ++dt)
                orow[dt * 16 + l15] = f2bf(accO[dt][r] * inv);
        }
    }
}

extern "C" void kernel_launch(void* const* d_in, const int* in_sizes, int n_in,
                              void* d_out, int out_size, void* d_ws, size_t ws_size,
                              hipStream_t stream) {
    const float* X   = (const float*)d_in[0];
    const float* lng = (const float*)d_in[1];
    const float* lnb = (const float*)d_in[2];
    const float* Wq  = (const float*)d_in[3];
    const float* bq  = (const float*)d_in[4];
    const float* Wk  = (const float*)d_in[5];
    const float* bk  = (const float*)d_in[6];
    const float* Wv  = (const float*)d_in[7];
    const float* bv  = (const float*)d_in[8];
    const float* Wo  = (const float*)d_in[9];
    const float* bo  = (const float*)d_in[10];
    float* out = (float*)d_out;

    char* p = (char*)d_ws;
    unsigned short* Xn  = (unsigned short*)p; p += (size_t)kM * kDM * 2;   // 16 MB
    unsigned short* Wqt = (unsigned short*)p; p += (size_t)kDM * kDM * 2;  //  8 MB (Wq|Wk|Wv contiguous)
    unsigned short* Wkt = (unsigned short*)p; p += (size_t)kDM * kDM * 2;
    unsigned short* Wvt = (unsigned short*)p; p += (size_t)kDM * kDM * 2;
    unsigned short* Wot = (unsigned short*)p; p += (size_t)kDM * kDM * 2;
    unsigned short* Qb  = (unsigned short*)p; p += (size_t)kM * kDM * 2;   // 16 MB
    unsigned short* Kb  = (unsigned short*)p; p += (size_t)kM * kDM * 2;   // 16 MB
    unsigned short* Vtb = (unsigned short*)p; p += (size_t)kM * kDM * 2;
    unsigned short* AV  = (unsigned short*)p; p += (size_t)kM * kDM * 2;
    unsigned short* Vtmp = AV;        // alias: consumed by vtr before attn writes AV
    float* biasc = (float*)Vtb;       // alias: consumed by qkv-gemm before vtr writes Vtb
    // split-K partials (32 MB each), from memory dead at Wo-GEMM time:
    //   Pk0 = Qb|Kb   (dead after attn)
    //   Pk1 = Xn|Wqt|Wkt (Xn dead after QKV GEMM; Wqt/Wkt dead after QKV GEMM;
    //         Wot -- the live B matrix -- is NOT covered)
    float* Pk0 = (float*)Qb;
    float* Pk1 = (float*)Xn;

    // log2(e)/sqrt(Dh): exp2-domain softmax
    const float qscale = 0.08838834764831845f * 1.4426950408889634f;

    ln_kernel<<<dim3(kM), dim3(256), 0, stream>>>(X, lng, lnb, Xn);
    wt_kernel<<<dim3(64, 64, 4), dim3(256), 0, stream>>>(Wq, Wk, Wv, Wo, Wqt, Wkt, Wvt, Wot);
    bias_pack<<<dim3(24), dim3(256), 0, stream>>>(bq, bk, bv, biasc);
    // fused QKV GEMM: N = 6144 over concatenated [Wqt|Wkt|Wvt]; m-tile fastest
    gemm_kernel<<<dim3(32, 48), dim3(256), 0, stream>>>(Xn, Wqt, biasc, Qb, Kb, Vtmp, qscale, 0);
    vtr_kernel<<<dim3(32, 2, 32), dim3(256), 0, stream>>>(Vtmp, Vtb);
    attn_kernel<<<dim3(32, 16), dim3(256), 0, stream>>>(Qb, Kb, Vtb, AV);
    // Wo GEMM: split-K=2 (1024 blocks = 4/CU) + reduce
    gemm_splitk<<<dim3(32, 16, 2), dim3(256), 0, stream>>>(AV, Wot, Pk0, Pk1);
    wo_reduce<<<dim3(kM * kDM / 4 / 256), dim3(256), 0, stream>>>(Pk0, Pk1, bo, out);
}